// Round 1
// baseline (10473.400 us; speedup 1.0000x reference)
//
#include <hip/hip_runtime.h>
#include <math.h>

#define Bb 128
#define Tt 25
#define Vv 10000
#define Ee 512
#define Aa 512
#define Hh 512
#define ENCc 2048
#define Pp 196
#define NSTEP 24
#define XDIM 3072   // [ctx(2048), h(512), dec(512)]

#define OUT_PREDS 0
#define OUT_CAPS  ((size_t)Bb*Tt*Vv)            // 32,000,000
#define OUT_LENS  (OUT_CAPS + (size_t)Bb*Tt)    // 32,003,200
#define OUT_SORT  (OUT_LENS + Bb)               // 32,003,328

__device__ __forceinline__ float sigm(float x) { return 1.0f / (1.0f + expf(-x)); }

// ---------------- sort + index maps + int outputs ----------------
__global__ void k_sort(const int* __restrict__ captions, const int* __restrict__ cap_lens,
                       int* sort_ind, int* lens_s, int* caps_s,
                       int* row_enc, int* row_emb, int* xoff,
                       int* logit_rowoff, int* logit_mask,
                       float* out)
{
    int b = threadIdx.x; // 0..127
    __shared__ int lens_sh[Bb];
    int len = cap_lens[b];
    lens_sh[b] = len;
    __syncthreads();
    // stable descending rank (matches jnp.argsort(-lens), stable)
    int r = 0;
    for (int k = 0; k < Bb; k++) {
        int lk = lens_sh[k];
        if (lk > len || (lk == len && k < b)) r++;
    }
    sort_ind[r] = b;
    lens_s[r] = len;
    for (int t = 0; t < Tt; t++) {
        int cv = captions[b * Tt + t];
        caps_s[r * Tt + t] = cv;
        out[OUT_CAPS + (size_t)r * Tt + t] = (float)cv;
    }
    out[OUT_LENS + r] = (float)len;
    out[OUT_SORT + r] = (float)b;
    __syncthreads();
    // row map for att_enc GEMM (sorted enc rows)
    for (int m = b; m < Bb * Pp; m += Bb) {
        int b2 = m / Pp, p = m % Pp;
        row_enc[m] = sort_ind[b2] * Pp + p;
    }
    // row map for att_d GEMM rows (t*B+b) -> token id; logits epilogue maps
    for (int m = b; m < NSTEP * Bb; m += Bb) {
        int t = m / Bb, bb = m % Bb;
        row_emb[m] = caps_s[bb * Tt + t];
        logit_rowoff[m] = (bb * Tt + (t + 1)) * Vv;
        logit_mask[m] = (lens_s[bb] > t + 1) ? 1 : 0;
    }
    for (int m = b; m < Bb; m += Bb) xoff[m] = m * XDIM;
}

// ---------------- preds[:,0,:] ----------------
__global__ void k_preds0(float* out)
{
    size_t i = (size_t)blockIdx.x * 256 + threadIdx.x;
    if (i >= (size_t)Bb * Vv) return;
    size_t b = i / Vv, v = i % Vv;
    out[b * Tt * Vv + v] = (v == 0) ? 1.0f : 0.0f;
}

// ---------------- enc mean (sorted) ----------------
__global__ void k_enc_mean(const float* __restrict__ enc, const int* __restrict__ sort_ind,
                           float* enc_mean)
{
    int b = blockIdx.y;
    int e = blockIdx.x * 256 + threadIdx.x;
    int src = sort_ind[b];
    const float* base = enc + (size_t)src * Pp * ENCc + e;
    float s = 0.0f;
    for (int p = 0; p < Pp; p++) s += base[(size_t)p * ENCc];
    enc_mean[(size_t)b * ENCc + e] = s / 196.0f;
}

// ---------------- generic C = A @ B^T (+bias) with optional epilogues ----------------
// A: (M,K) row-major (lda), optionally row-remapped; B: (N,K) row-major.
// mul_src: out = sigmoid(acc+bias)*mul_src[m*N+n]   (gate fusion)
// mmask:   out = mask ? val : 0                      (logits masking)
template<int BM, int BN, int TM, int TN>
__global__ void gemm_tn(const float* __restrict__ Amat, const float* __restrict__ Bmat,
                        const float* __restrict__ bias, float* __restrict__ C,
                        int M, int N, int K, int lda,
                        const int* __restrict__ a_rowmap,
                        const int* __restrict__ c_rowoff,
                        const float* __restrict__ mul_src,
                        const int* __restrict__ mmask)
{
    constexpr int BK = 16;
    __shared__ float As[BK][BM + 1];
    __shared__ float Bs[BK][BN + 1];
    int bm = blockIdx.y * BM;
    int bn = blockIdx.x * BN;
    int tid = threadIdx.x;
    int tx = tid % (BN / TN);
    int ty = tid / (BN / TN);
    float acc[TM][TN];
    #pragma unroll
    for (int i = 0; i < TM; i++)
        #pragma unroll
        for (int j = 0; j < TN; j++) acc[i][j] = 0.0f;

    for (int k0 = 0; k0 < K; k0 += BK) {
        for (int idx = tid; idx < BM * BK; idx += 256) {
            int m = idx / BK, kk = idx % BK;
            int gm = bm + m;
            float v = 0.0f;
            if (gm < M) {
                int row = a_rowmap ? a_rowmap[gm] : gm;
                v = Amat[(size_t)row * lda + k0 + kk];
            }
            As[kk][m] = v;
        }
        for (int idx = tid; idx < BN * BK; idx += 256) {
            int n = idx / BK, kk = idx % BK;
            int gn = bn + n;
            Bs[kk][n] = (gn < N) ? Bmat[(size_t)gn * K + k0 + kk] : 0.0f;
        }
        __syncthreads();
        #pragma unroll
        for (int kk = 0; kk < BK; kk++) {
            float af[TM], bf[TN];
            #pragma unroll
            for (int i = 0; i < TM; i++) af[i] = As[kk][ty * TM + i];
            #pragma unroll
            for (int j = 0; j < TN; j++) bf[j] = Bs[kk][tx * TN + j];
            #pragma unroll
            for (int i = 0; i < TM; i++)
                #pragma unroll
                for (int j = 0; j < TN; j++) acc[i][j] += af[i] * bf[j];
        }
        __syncthreads();
    }
    #pragma unroll
    for (int i = 0; i < TM; i++) {
        int gm = bm + ty * TM + i;
        if (gm >= M) continue;
        size_t rowoff = c_rowoff ? (size_t)c_rowoff[gm] : (size_t)gm * N;
        int msk = mmask ? mmask[gm] : 1;
        #pragma unroll
        for (int j = 0; j < TN; j++) {
            int gn = bn + tx * TN + j;
            if (gn >= N) continue;
            float v = acc[i][j] + (bias ? bias[gn] : 0.0f);
            if (mul_src) v = sigm(v) * mul_src[(size_t)gm * N + gn];
            if (!msk) v = 0.0f;
            C[rowoff + gn] = v;
        }
    }
}

// ---------------- scores for all t: relu(att_enc + att_d) . fin ----------------
#define PCHUNK 7
__global__ void k_scores(const float* __restrict__ att_enc_buf, const float* __restrict__ att_d,
                         const float* __restrict__ fin_W, const float* __restrict__ fin_b,
                         float* __restrict__ scores)
{
    int b = blockIdx.y;
    int p0 = blockIdx.x * PCHUNK;
    __shared__ float attd_s[NSTEP][Aa];
    __shared__ float fin_s[Aa];
    __shared__ float row_s[Aa];
    int tid = threadIdx.x;
    for (int idx = tid; idx < NSTEP * Aa; idx += 256) {
        int t = idx / Aa, a = idx % Aa;
        attd_s[t][a] = att_d[((size_t)t * Bb + b) * Aa + a];
    }
    for (int idx = tid; idx < Aa; idx += 256) fin_s[idx] = fin_W[idx];
    __syncthreads();
    float fb = fin_b[0];
    int lane = tid & 63, wave = tid >> 6;
    for (int pi = 0; pi < PCHUNK; pi++) {
        int p = p0 + pi;
        if (p >= Pp) break;
        __syncthreads();
        for (int idx = tid; idx < Aa; idx += 256)
            row_s[idx] = att_enc_buf[((size_t)b * Pp + p) * Aa + idx];
        __syncthreads();
        for (int t = wave; t < NSTEP; t += 4) {
            float acc = 0.0f;
            for (int a = lane; a < Aa; a += 64) {
                float v = row_s[a] + attd_s[t][a];
                acc += fmaxf(v, 0.0f) * fin_s[a];
            }
            #pragma unroll
            for (int off = 32; off > 0; off >>= 1) acc += __shfl_down(acc, off);
            if (lane == 0) scores[((size_t)t * Bb + b) * Pp + p] = acc + fb;
        }
    }
}

// ---------------- softmax over P per (t,b), in place ----------------
__global__ void k_softmax(float* scores)
{
    int tb = blockIdx.x;
    float* row = scores + (size_t)tb * Pp;
    int lane = threadIdx.x; // 64
    float v[4];
    float mx = -1e30f;
    #pragma unroll
    for (int i = 0; i < 4; i++) {
        int p = lane + i * 64;
        v[i] = (p < Pp) ? row[p] : -1e30f;
        mx = fmaxf(mx, v[i]);
    }
    #pragma unroll
    for (int off = 32; off > 0; off >>= 1) mx = fmaxf(mx, __shfl_down(mx, off));
    mx = __shfl(mx, 0);
    float s = 0.0f;
    #pragma unroll
    for (int i = 0; i < 4; i++) {
        int p = lane + i * 64;
        v[i] = (p < Pp) ? expf(v[i] - mx) : 0.0f;
        s += v[i];
    }
    #pragma unroll
    for (int off = 32; off > 0; off >>= 1) s += __shfl_down(s, off);
    s = __shfl(s, 0);
    float inv = 1.0f / s;
    #pragma unroll
    for (int i = 0; i < 4; i++) {
        int p = lane + i * 64;
        if (p < Pp) row[p] = v[i] * inv;
    }
}

// ---------------- ctx_raw[t,b,:] = sum_p wts[t,b,p] * enc_sorted[b,p,:] ----------------
__global__ void k_ctx(const float* __restrict__ enc, const int* __restrict__ sort_ind,
                      const float* __restrict__ wts, float* __restrict__ ctx_raw)
{
    int b = blockIdx.y;
    int e = blockIdx.x * 256 + threadIdx.x;
    __shared__ float w_s[NSTEP][Pp];
    int tid = threadIdx.x;
    for (int idx = tid; idx < NSTEP * Pp; idx += 256) {
        int t = idx / Pp, p = idx % Pp;
        w_s[t][p] = wts[((size_t)t * Bb + b) * Pp + p];
    }
    __syncthreads();
    int src = sort_ind[b];
    const float* base = enc + (size_t)src * Pp * ENCc + e;
    float acc[NSTEP];
    #pragma unroll
    for (int t = 0; t < NSTEP; t++) acc[t] = 0.0f;
    for (int p = 0; p < Pp; p++) {
        float v = base[(size_t)p * ENCc];
        #pragma unroll
        for (int t = 0; t < NSTEP; t++) acc[t] += w_s[t][p] * v;
    }
    for (int t = 0; t < NSTEP; t++)
        ctx_raw[((size_t)t * Bb + b) * ENCc + e] = acc[t];
}

// ---------------- W_cat = [W_ih[:, :2048] | W_hh | W_ih[:, 2048:]], bias_cat ----------------
__global__ void k_wcat(const float* __restrict__ W_ih, const float* __restrict__ W_hh,
                       const float* __restrict__ b_ih, const float* __restrict__ b_hh,
                       float* __restrict__ W_cat, float* __restrict__ bias_cat)
{
    int i = blockIdx.x * 256 + threadIdx.x;
    int total = 2048 * XDIM;
    if (i < total) {
        int n = i / XDIM, k = i % XDIM;
        float v;
        if (k < 2048)      v = W_ih[(size_t)n * 2560 + k];
        else if (k < 2560) v = W_hh[(size_t)n * 512 + (k - 2048)];
        else               v = W_ih[(size_t)n * 2560 + 2048 + (k - 2560)];
        W_cat[i] = v;
    }
    if (i < 2048) bias_cat[i] = b_ih[i] + b_hh[i];
}

// ---------------- init x with h0 and dec_0 ----------------
__global__ void k_init_x(const float* __restrict__ h, const float* __restrict__ emb_W,
                         const int* __restrict__ caps_s, float* __restrict__ x)
{
    int i = blockIdx.x * 256 + threadIdx.x; // B*512
    int b = i / Hh, j = i % Hh;
    x[(size_t)b * XDIM + 2048 + j] = h[i];
    x[(size_t)b * XDIM + 2560 + j] = emb_W[(size_t)caps_s[b * Tt] * Ee + j];
}

// ---------------- LSTM pointwise + state update + next dec ----------------
__global__ void k_lstm(const float* __restrict__ gates, float* __restrict__ h, float* __restrict__ c,
                       float* __restrict__ h_all, float* __restrict__ x,
                       const float* __restrict__ emb_W, const int* __restrict__ caps_s,
                       const int* __restrict__ lens_s, int t)
{
    int i = blockIdx.x * 256 + threadIdx.x; // B*512
    int b = i / Hh, j = i % Hh;
    float gi = gates[(size_t)b * 2048 + j];
    float gf = gates[(size_t)b * 2048 + 512 + j];
    float gg = gates[(size_t)b * 2048 + 1024 + j];
    float go = gates[(size_t)b * 2048 + 1536 + j];
    float cn = sigm(gf) * c[i] + sigm(gi) * tanhf(gg);
    float hn = sigm(go) * tanhf(cn);
    bool act = lens_s[b] > (t + 1);
    float hv = act ? hn : h[i];
    float cv = act ? cn : c[i];
    h[i] = hv;
    c[i] = cv;
    h_all[((size_t)t * Bb + b) * Hh + j] = hv;
    x[(size_t)b * XDIM + 2048 + j] = hv;
    if (t + 1 < NSTEP)
        x[(size_t)b * XDIM + 2560 + j] = emb_W[(size_t)caps_s[b * Tt + (t + 1)] * Ee + j];
}

extern "C" void kernel_launch(void* const* d_in, const int* in_sizes, int n_in,
                              void* d_out, int out_size, void* d_ws, size_t ws_size,
                              hipStream_t stream)
{
    const int*   captions    = (const int*)d_in[0];
    const float* encoder_out = (const float*)d_in[1];
    const int*   cap_lens    = (const int*)d_in[2];
    const float* emb_W       = (const float*)d_in[3];
    const float* att_enc_W   = (const float*)d_in[4];
    const float* att_enc_b   = (const float*)d_in[5];
    const float* att_dec_W   = (const float*)d_in[6];
    const float* att_dec_b   = (const float*)d_in[7];
    const float* att_fin_W   = (const float*)d_in[8];
    const float* att_fin_b   = (const float*)d_in[9];
    const float* f_beta_W    = (const float*)d_in[10];
    const float* f_beta_b    = (const float*)d_in[11];
    const float* W_ih        = (const float*)d_in[12];
    const float* b_ih        = (const float*)d_in[13];
    const float* W_hh        = (const float*)d_in[14];
    const float* b_hh        = (const float*)d_in[15];
    const float* lin_W       = (const float*)d_in[16];
    const float* lin_b       = (const float*)d_in[17];
    const float* h_init_W    = (const float*)d_in[18];
    const float* h_init_b    = (const float*)d_in[19];
    const float* c_init_W    = (const float*)d_in[20];
    const float* c_init_b    = (const float*)d_in[21];
    float* out = (float*)d_out;

    // workspace carve (floats then ints)
    float* f = (float*)d_ws;
    float* att_enc_buf = f; f += (size_t)Bb * Pp * Aa;        // 12,845,056
    float* ctx_raw     = f; f += (size_t)NSTEP * Bb * ENCc;   // 6,291,456
    float* att_d       = f; f += (size_t)NSTEP * Bb * Aa;     // 1,572,864
    float* h_all       = f; f += (size_t)NSTEP * Bb * Hh;     // 1,572,864
    float* wts         = f; f += (size_t)NSTEP * Bb * Pp;     // 602,112
    float* enc_mean    = f; f += (size_t)Bb * ENCc;           // 262,144
    float* hbuf        = f; f += (size_t)Bb * Hh;
    float* cbuf        = f; f += (size_t)Bb * Hh;
    float* xbuf        = f; f += (size_t)Bb * XDIM;
    float* gates_buf   = f; f += (size_t)Bb * 2048;
    float* W_cat       = f; f += (size_t)2048 * XDIM;         // 6,291,456
    float* bias_cat    = f; f += 2048;
    int* ip = (int*)f;
    int* sort_ind     = ip; ip += Bb;
    int* lens_s       = ip; ip += Bb;
    int* caps_s       = ip; ip += Bb * Tt;
    int* row_enc      = ip; ip += Bb * Pp;
    int* row_emb      = ip; ip += NSTEP * Bb;
    int* xoff         = ip; ip += Bb;
    int* logit_rowoff = ip; ip += NSTEP * Bb;
    int* logit_mask   = ip; ip += NSTEP * Bb;

    // 1. sort + maps + int outputs
    k_sort<<<1, Bb, 0, stream>>>(captions, cap_lens, sort_ind, lens_s, caps_s,
                                 row_enc, row_emb, xoff, logit_rowoff, logit_mask, out);
    // 2. preds[:,0,:]
    k_preds0<<<(Bb * Vv + 255) / 256, 256, 0, stream>>>(out);
    // 3. enc mean
    k_enc_mean<<<dim3(ENCc / 256, Bb), 256, 0, stream>>>(encoder_out, sort_ind, enc_mean);
    // 4. h0 / c0
    gemm_tn<32,32,2,2><<<dim3(Hh / 32, Bb / 32), 256, 0, stream>>>(
        enc_mean, h_init_W, h_init_b, hbuf, Bb, Hh, ENCc, ENCc, nullptr, nullptr, nullptr, nullptr);
    gemm_tn<32,32,2,2><<<dim3(Hh / 32, Bb / 32), 256, 0, stream>>>(
        enc_mean, c_init_W, c_init_b, cbuf, Bb, Hh, ENCc, ENCc, nullptr, nullptr, nullptr, nullptr);
    // 5. att_enc = enc_sorted @ att_enc_W^T  (M=25088,N=512,K=2048)
    gemm_tn<64,64,4,4><<<dim3(Aa / 64, (Bb * Pp) / 64), 256, 0, stream>>>(
        encoder_out, att_enc_W, att_enc_b, att_enc_buf, Bb * Pp, Aa, ENCc, ENCc,
        row_enc, nullptr, nullptr, nullptr);
    // 6. att_d for all t  (M=3072,N=512,K=512), A rows gathered from emb_W
    gemm_tn<64,64,4,4><<<dim3(Aa / 64, (NSTEP * Bb) / 64), 256, 0, stream>>>(
        emb_W, att_dec_W, att_dec_b, att_d, NSTEP * Bb, Aa, Ee, Ee,
        row_emb, nullptr, nullptr, nullptr);
    // 7. scores for all t
    k_scores<<<dim3(Pp / PCHUNK, Bb), 256, 0, stream>>>(att_enc_buf, att_d, att_fin_W, att_fin_b, wts);
    // 8. softmax
    k_softmax<<<NSTEP * Bb, 64, 0, stream>>>(wts);
    // 9. ctx_raw
    k_ctx<<<dim3(ENCc / 256, Bb), 256, 0, stream>>>(encoder_out, sort_ind, wts, ctx_raw);
    // 10. W_cat / bias_cat
    k_wcat<<<(2048 * XDIM + 255) / 256, 256, 0, stream>>>(W_ih, W_hh, b_ih, b_hh, W_cat, bias_cat);
    // 11. x init (h0, dec_0)
    k_init_x<<<(Bb * Hh) / 256, 256, 0, stream>>>(hbuf, emb_W, caps_s, xbuf);

    // 12. sequential LSTM loop
    for (int t = 0; t < NSTEP; t++) {
        // gate = sigmoid(h @ f_beta_W^T + b), fused ctx = gate * ctx_raw[t]  -> x[:, :2048]
        gemm_tn<32,32,2,2><<<dim3(ENCc / 32, Bb / 32), 256, 0, stream>>>(
            hbuf, f_beta_W, f_beta_b, xbuf, Bb, ENCc, Hh, Hh,
            nullptr, xoff, ctx_raw + (size_t)t * Bb * ENCc, nullptr);
        // gates = x @ W_cat^T + bias_cat   (M=128,N=2048,K=3072)
        gemm_tn<32,32,2,2><<<dim3(2048 / 32, Bb / 32), 256, 0, stream>>>(
            xbuf, W_cat, bias_cat, gates_buf, Bb, 2048, XDIM, XDIM,
            nullptr, nullptr, nullptr, nullptr);
        // pointwise LSTM + state update + stage next dec
        k_lstm<<<(Bb * Hh) / 256, 256, 0, stream>>>(gates_buf, hbuf, cbuf, h_all, xbuf,
                                                    emb_W, caps_s, lens_s, t);
    }

    // 13. logits for all t: h_all @ lin_W^T + lin_b, masked, scattered into preds
    gemm_tn<64,64,4,4><<<dim3((Vv + 63) / 64, (NSTEP * Bb) / 64), 256, 0, stream>>>(
        h_all, lin_W, lin_b, out, NSTEP * Bb, Vv, Hh, Hh,
        nullptr, logit_rowoff, nullptr, logit_mask);
}

// Round 3
// 3530.330 us; speedup vs baseline: 2.9667x; 2.9667x over previous
//
#include <hip/hip_runtime.h>
#include <math.h>

#define Bb 128
#define Tt 25
#define Vv 10000
#define Ee 512
#define Aa 512
#define Hh 512
#define ENCc 2048
#define Pp 196
#define NSTEP 24
#define XDIM 3072   // [ctx(2048), h(512), dec(512)]
#define NPAD 10112  // 79*128

#define OUT_CAPS  ((size_t)Bb*Tt*Vv)            // 32,000,000
#define OUT_LENS  (OUT_CAPS + (size_t)Bb*Tt)    // 32,003,200
#define OUT_SORT  (OUT_LENS + Bb)               // 32,003,328

typedef __bf16 bf16x8 __attribute__((ext_vector_type(8)));
typedef __bf16 bf16x4 __attribute__((ext_vector_type(4)));
typedef float  f32x4  __attribute__((ext_vector_type(4)));

__device__ __forceinline__ float sigm(float x) { return 1.0f / (1.0f + expf(-x)); }

// ---------------- sort + index maps + int outputs ----------------
__global__ void k_sort(const int* __restrict__ captions, const int* __restrict__ cap_lens,
                       int* sort_ind, int* lens_s, int* caps_s,
                       int* row_emb, int* logit_rowoff, int* logit_mask,
                       float* out)
{
    int b = threadIdx.x; // 0..127
    __shared__ int lens_sh[Bb];
    int len = cap_lens[b];
    lens_sh[b] = len;
    __syncthreads();
    int r = 0;
    for (int k = 0; k < Bb; k++) {
        int lk = lens_sh[k];
        if (lk > len || (lk == len && k < b)) r++;
    }
    sort_ind[r] = b;
    lens_s[r] = len;
    for (int t = 0; t < Tt; t++) {
        int cv = captions[b * Tt + t];
        caps_s[r * Tt + t] = cv;
        out[OUT_CAPS + (size_t)r * Tt + t] = (float)cv;
    }
    out[OUT_LENS + r] = (float)len;
    out[OUT_SORT + r] = (float)b;
    __syncthreads();
    for (int m = b; m < NSTEP * Bb; m += Bb) {
        int t = m / Bb, bb = m % Bb;
        row_emb[m] = caps_s[bb * Tt + t];
        logit_rowoff[m] = (bb * Tt + (t + 1)) * Vv;
        logit_mask[m] = (lens_s[bb] > t + 1) ? 1 : 0;
    }
}

__global__ void k_preds0(float* out)
{
    size_t i = (size_t)blockIdx.x * 256 + threadIdx.x;
    if (i >= (size_t)Bb * Vv) return;
    size_t b = i / Vv, v = i % Vv;
    out[b * Tt * Vv + v] = (v == 0) ? 1.0f : 0.0f;
}

// ---------------- conversions ----------------
__global__ void k_cvt_enc(const float* __restrict__ src, const int* __restrict__ sind,
                          __bf16* __restrict__ dst)
{
    int row = blockIdx.y;                       // 0..25087 sorted row
    int e4 = blockIdx.x * 256 + threadIdx.x;    // 0..511
    int b = row / Pp, p = row % Pp;
    const float4 v = *(const float4*)(src + ((size_t)(sind[b] * Pp + p)) * ENCc + e4 * 4);
    bf16x4 o = { (__bf16)v.x, (__bf16)v.y, (__bf16)v.z, (__bf16)v.w };
    *(bf16x4*)(dst + (size_t)row * ENCc + e4 * 4) = o;
}

__global__ void k_cvt(const float* __restrict__ src, __bf16* __restrict__ dst, int n4)
{
    int i = blockIdx.x * 256 + threadIdx.x;
    if (i >= n4) return;
    const float4 v = *(const float4*)(src + (size_t)i * 4);
    bf16x4 o = { (__bf16)v.x, (__bf16)v.y, (__bf16)v.z, (__bf16)v.w };
    *(bf16x4*)(dst + (size_t)i * 4) = o;
}

__global__ void k_cvt_lin(const float* __restrict__ src, __bf16* __restrict__ dst)
{
    int i = blockIdx.x * 256 + threadIdx.x;     // over NPAD*128
    if (i >= NPAD * 128) return;
    int row = i >> 7, e = (i & 127) * 4;
    bf16x4 o;
    if (row < Vv) {
        const float4 v = *(const float4*)(src + (size_t)row * Hh + e);
        o = bf16x4{ (__bf16)v.x, (__bf16)v.y, (__bf16)v.z, (__bf16)v.w };
    } else {
        o = bf16x4{ (__bf16)0.f, (__bf16)0.f, (__bf16)0.f, (__bf16)0.f };
    }
    *(bf16x4*)(dst + (size_t)row * Hh + e) = o;
}

__global__ void k_cvt_emb(const float* __restrict__ emb_W, const int* __restrict__ row_emb,
                          __bf16* __restrict__ dst)
{
    int i = blockIdx.x * 256 + threadIdx.x;     // over 3072*128
    int row = i >> 7, e = (i & 127) * 4;
    const float4 v = *(const float4*)(emb_W + (size_t)row_emb[row] * Ee + e);
    bf16x4 o = { (__bf16)v.x, (__bf16)v.y, (__bf16)v.z, (__bf16)v.w };
    *(bf16x4*)(dst + (size_t)row * Ee + e) = o;
}

// ---------------- enc mean (bf16 in, bf16 out) ----------------
__global__ void k_enc_mean(const __bf16* __restrict__ enc, __bf16* __restrict__ emean)
{
    int b = blockIdx.y;
    int e = blockIdx.x * 256 + threadIdx.x;
    const __bf16* base = enc + (size_t)b * Pp * ENCc + e;
    float s = 0.0f;
    for (int p = 0; p < Pp; p++) s += (float)base[(size_t)p * ENCc];
    emean[(size_t)b * ENCc + e] = (__bf16)(s / 196.0f);
}

// ---------------- W_cat (bf16) = [W_ih[:, :2048] | W_hh | W_ih[:, 2048:]] ----------------
__global__ void k_wcat(const float* __restrict__ W_ih, const float* __restrict__ W_hh,
                       __bf16* __restrict__ W_cat)
{
    int n = blockIdx.y;
    int k4 = blockIdx.x * 256 + threadIdx.x;    // 0..767
    int k = k4 * 4;
    float4 v;
    if (k < 2048)      v = *(const float4*)(W_ih + (size_t)n * 2560 + k);
    else if (k < 2560) v = *(const float4*)(W_hh + (size_t)n * 512 + (k - 2048));
    else               v = *(const float4*)(W_ih + (size_t)n * 2560 + 2048 + (k - 2560));
    bf16x4 o = { (__bf16)v.x, (__bf16)v.y, (__bf16)v.z, (__bf16)v.w };
    *(bf16x4*)(W_cat + (size_t)n * XDIM + k) = o;
}

// ---------------- MFMA GEMM: C = A @ B^T (+bias), 128x128 tile, BK=32 ----------------
// MODE 0: f32 out row-major (stride Nout)
// MODE 1: bf16 out row-major
// MODE 2: f32 out, row scatter (c_rowoff) + mask, col-bounds vs N
// MODE 3: bf16 out stride Nout, v = sigmoid(v) * mul_src[row*N+col]
template<int MODE>
__launch_bounds__(256)
__global__ void mfma_gemm(const __bf16* __restrict__ A, const __bf16* __restrict__ B,
                          const float* __restrict__ bias, void* __restrict__ Cout,
                          int M, int N, int K, int Nout,
                          const int* __restrict__ c_rowoff,
                          const int* __restrict__ mmask,
                          const float* __restrict__ mul_src)
{
    __shared__ __bf16 sA[128 * 32];
    __shared__ __bf16 sB[128 * 32];
    const int tid = threadIdx.x;
    const int lane = tid & 63;
    const int wave = tid >> 6;
    const int m0 = blockIdx.y * 128, n0 = blockIdx.x * 128;
    const int wr = (wave & 1) * 64, wc = (wave >> 1) * 64;
    f32x4 acc[4][4] = {};
    const __bf16* Aptr = A + (size_t)m0 * K;
    const __bf16* Bptr = B + (size_t)n0 * K;
    const int c0 = tid, c1 = tid + 256;
    const int ar0 = c0 >> 2, ak0 = (c0 & 3) * 8;
    const int ar1 = c1 >> 2, ak1 = (c1 & 3) * 8;
    const int kq = (lane >> 4) * 8, mr = lane & 15;

    for (int k0 = 0; k0 < K; k0 += 32) {
        __builtin_amdgcn_global_load_lds(
            (const __attribute__((address_space(1))) void*)(Aptr + (size_t)ar0 * K + k0 + ak0),
            (__attribute__((address_space(3))) void*)(sA + c0 * 8), 16, 0, 0);
        __builtin_amdgcn_global_load_lds(
            (const __attribute__((address_space(1))) void*)(Aptr + (size_t)ar1 * K + k0 + ak1),
            (__attribute__((address_space(3))) void*)(sA + c1 * 8), 16, 0, 0);
        __builtin_amdgcn_global_load_lds(
            (const __attribute__((address_space(1))) void*)(Bptr + (size_t)ar0 * K + k0 + ak0),
            (__attribute__((address_space(3))) void*)(sB + c0 * 8), 16, 0, 0);
        __builtin_amdgcn_global_load_lds(
            (const __attribute__((address_space(1))) void*)(Bptr + (size_t)ar1 * K + k0 + ak1),
            (__attribute__((address_space(3))) void*)(sB + c1 * 8), 16, 0, 0);
        __syncthreads();
        bf16x8 af[4], bfr[4];
        #pragma unroll
        for (int i = 0; i < 4; i++)
            af[i] = *(const bf16x8*)(sA + (wr + i * 16 + mr) * 32 + kq);
        #pragma unroll
        for (int j = 0; j < 4; j++)
            bfr[j] = *(const bf16x8*)(sB + (wc + j * 16 + mr) * 32 + kq);
        #pragma unroll
        for (int i = 0; i < 4; i++)
            #pragma unroll
            for (int j = 0; j < 4; j++)
                acc[i][j] = __builtin_amdgcn_mfma_f32_16x16x32_bf16(af[i], bfr[j], acc[i][j], 0, 0, 0);
        __syncthreads();
    }

    const int rq = (lane >> 4) * 4, cq = lane & 15;
    #pragma unroll
    for (int i = 0; i < 4; i++) {
        #pragma unroll
        for (int j = 0; j < 4; j++) {
            #pragma unroll
            for (int r = 0; r < 4; r++) {
                int row = m0 + wr + i * 16 + rq + r;
                int col = n0 + wc + j * 16 + cq;
                if (MODE == 2 && col >= N) continue;
                float v = acc[i][j][r] + (bias ? bias[col] : 0.0f);
                size_t ro = c_rowoff ? (size_t)c_rowoff[row] : (size_t)row * Nout;
                if (MODE == 3) {
                    v = sigm(v) * mul_src[(size_t)row * N + col];
                    ((__bf16*)Cout)[ro + col] = (__bf16)v;
                } else if (MODE == 2) {
                    if (!mmask[row]) v = 0.0f;
                    ((float*)Cout)[ro + col] = v;
                } else if (MODE == 1) {
                    ((__bf16*)Cout)[ro + col] = (__bf16)v;
                } else {
                    ((float*)Cout)[ro + col] = v;
                }
            }
        }
    }
}

// ---------------- scores for all t: relu(att_enc + att_d) . fin ----------------
#define PCHUNK 7
__global__ void k_scores(const __bf16* __restrict__ att_enc_buf, const float* __restrict__ att_d,
                         const float* __restrict__ fin_W, const float* __restrict__ fin_b,
                         float* __restrict__ scores)
{
    int b = blockIdx.y;
    int p0 = blockIdx.x * PCHUNK;
    __shared__ float attd_s[NSTEP][Aa];
    __shared__ float fin_s[Aa];
    __shared__ float row_s[Aa];
    int tid = threadIdx.x;
    for (int idx = tid; idx < NSTEP * Aa; idx += 256) {
        int t = idx / Aa, a = idx % Aa;
        attd_s[t][a] = att_d[((size_t)t * Bb + b) * Aa + a];
    }
    for (int idx = tid; idx < Aa; idx += 256) fin_s[idx] = fin_W[idx];
    __syncthreads();
    float fb = fin_b[0];
    int lane = tid & 63, wave = tid >> 6;
    for (int pi = 0; pi < PCHUNK; pi++) {
        int p = p0 + pi;
        if (p >= Pp) break;
        __syncthreads();
        for (int idx = tid; idx < Aa; idx += 256)
            row_s[idx] = (float)att_enc_buf[((size_t)b * Pp + p) * Aa + idx];
        __syncthreads();
        for (int t = wave; t < NSTEP; t += 4) {
            float acc = 0.0f;
            for (int a = lane; a < Aa; a += 64) {
                float v = row_s[a] + attd_s[t][a];
                acc += fmaxf(v, 0.0f) * fin_s[a];
            }
            #pragma unroll
            for (int off = 32; off > 0; off >>= 1) acc += __shfl_down(acc, off);
            if (lane == 0) scores[((size_t)t * Bb + b) * Pp + p] = acc + fb;
        }
    }
}

__global__ void k_softmax(float* scores)
{
    int tb = blockIdx.x;
    float* row = scores + (size_t)tb * Pp;
    int lane = threadIdx.x; // 64
    float v[4];
    float mx = -1e30f;
    #pragma unroll
    for (int i = 0; i < 4; i++) {
        int p = lane + i * 64;
        v[i] = (p < Pp) ? row[p] : -1e30f;
        mx = fmaxf(mx, v[i]);
    }
    #pragma unroll
    for (int off = 32; off > 0; off >>= 1) mx = fmaxf(mx, __shfl_down(mx, off));
    mx = __shfl(mx, 0);
    float s = 0.0f;
    #pragma unroll
    for (int i = 0; i < 4; i++) {
        int p = lane + i * 64;
        v[i] = (p < Pp) ? expf(v[i] - mx) : 0.0f;
        s += v[i];
    }
    #pragma unroll
    for (int off = 32; off > 0; off >>= 1) s += __shfl_down(s, off);
    s = __shfl(s, 0);
    float inv = 1.0f / s;
    #pragma unroll
    for (int i = 0; i < 4; i++) {
        int p = lane + i * 64;
        if (p < Pp) row[p] = v[i] * inv;
    }
}

// ---------------- ctx_raw[t,b,:] = sum_p wts[t,b,p] * enc_s[b,p,:] ----------------
__global__ void k_ctx(const __bf16* __restrict__ enc, const float* __restrict__ wts,
                      float* __restrict__ ctx_raw)
{
    int b = blockIdx.y;
    int e = blockIdx.x * 256 + threadIdx.x;
    __shared__ float w_s[NSTEP][Pp];
    int tid = threadIdx.x;
    for (int idx = tid; idx < NSTEP * Pp; idx += 256) {
        int t = idx / Pp, p = idx % Pp;
        w_s[t][p] = wts[((size_t)t * Bb + b) * Pp + p];
    }
    __syncthreads();
    const __bf16* base = enc + (size_t)b * Pp * ENCc + e;
    float acc[NSTEP];
    #pragma unroll
    for (int t = 0; t < NSTEP; t++) acc[t] = 0.0f;
    for (int p = 0; p < Pp; p++) {
        float v = (float)base[(size_t)p * ENCc];
        #pragma unroll
        for (int t = 0; t < NSTEP; t++) acc[t] += w_s[t][p] * v;
    }
    for (int t = 0; t < NSTEP; t++)
        ctx_raw[((size_t)t * Bb + b) * ENCc + e] = acc[t];
}

// ---------------- init x0: h and dec sections ----------------
__global__ void k_init_x(const __bf16* __restrict__ h0, const __bf16* __restrict__ embg,
                         __bf16* __restrict__ x)
{
    int i = blockIdx.x * 256 + threadIdx.x; // B*512
    int b = i >> 9, j = i & 511;
    x[(size_t)b * XDIM + 2048 + j] = h0[i];
    x[(size_t)b * XDIM + 2560 + j] = embg[i];
}

// ---------------- LSTM pointwise ----------------
__global__ void k_lstm(const float* __restrict__ gates, float* __restrict__ c,
                       const __bf16* __restrict__ h_prev, __bf16* __restrict__ h_out,
                       __bf16* __restrict__ x_next, const __bf16* __restrict__ emb_next,
                       const float* __restrict__ b_ih, const float* __restrict__ b_hh,
                       const int* __restrict__ lens_s, int t)
{
    int i = blockIdx.x * 256 + threadIdx.x; // B*512
    int b = i >> 9, j = i & 511;
    float gi = gates[(size_t)b * 2048 + j]        + b_ih[j]        + b_hh[j];
    float gf = gates[(size_t)b * 2048 + 512 + j]  + b_ih[512 + j]  + b_hh[512 + j];
    float gg = gates[(size_t)b * 2048 + 1024 + j] + b_ih[1024 + j] + b_hh[1024 + j];
    float go = gates[(size_t)b * 2048 + 1536 + j] + b_ih[1536 + j] + b_hh[1536 + j];
    float cn = sigm(gf) * c[i] + sigm(gi) * tanhf(gg);
    float hn = sigm(go) * tanhf(cn);
    bool act = lens_s[b] > (t + 1);
    __bf16 hv = act ? (__bf16)hn : h_prev[i];
    if (act) c[i] = cn;
    h_out[i] = hv;
    x_next[(size_t)b * XDIM + 2048 + j] = hv;
    if (emb_next) x_next[(size_t)b * XDIM + 2560 + j] = emb_next[i];
}

extern "C" void kernel_launch(void* const* d_in, const int* in_sizes, int n_in,
                              void* d_out, int out_size, void* d_ws, size_t ws_size,
                              hipStream_t stream)
{
    const int*   captions    = (const int*)d_in[0];
    const float* encoder_out = (const float*)d_in[1];
    const int*   cap_lens    = (const int*)d_in[2];
    const float* emb_W       = (const float*)d_in[3];
    const float* att_enc_W   = (const float*)d_in[4];
    const float* att_enc_b   = (const float*)d_in[5];
    const float* att_dec_W   = (const float*)d_in[6];
    const float* att_dec_b   = (const float*)d_in[7];
    const float* att_fin_W   = (const float*)d_in[8];
    const float* att_fin_b   = (const float*)d_in[9];
    const float* f_beta_W    = (const float*)d_in[10];
    const float* f_beta_b    = (const float*)d_in[11];
    const float* W_ih        = (const float*)d_in[12];
    const float* b_ih        = (const float*)d_in[13];
    const float* W_hh        = (const float*)d_in[14];
    const float* b_hh        = (const float*)d_in[15];
    const float* lin_W       = (const float*)d_in[16];
    const float* lin_b       = (const float*)d_in[17];
    const float* h_init_W    = (const float*)d_in[18];
    const float* h_init_b    = (const float*)d_in[19];
    const float* c_init_W    = (const float*)d_in[20];
    const float* c_init_b    = (const float*)d_in[21];
    float* out = (float*)d_out;

    // ---- workspace carve: f32 first, then bf16 (16B-aligned sizes), then ints ----
    float* f = (float*)d_ws;
    float* ctx_raw = f; f += (size_t)NSTEP * Bb * ENCc;   // 6,291,456
    float* att_d   = f; f += (size_t)NSTEP * Bb * Aa;     // 1,572,864
    float* wts     = f; f += (size_t)NSTEP * Bb * Pp;     // 602,112
    float* cbuf    = f; f += (size_t)Bb * Hh;             // 65,536
    float* gates   = f; f += (size_t)Bb * 2048;           // 262,144
    __bf16* bp = (__bf16*)f;
    __bf16* enc_s  = bp; bp += (size_t)Bb * Pp * ENCc;    // 51,380,224
    __bf16* attenc = bp; bp += (size_t)Bb * Pp * Aa;      // 12,845,056
    __bf16* attW   = bp; bp += (size_t)Aa * ENCc;
    __bf16* attdW  = bp; bp += (size_t)Aa * Ee;
    __bf16* fbW    = bp; bp += (size_t)ENCc * Hh;
    __bf16* hiW    = bp; bp += (size_t)Hh * ENCc;
    __bf16* ciW    = bp; bp += (size_t)Hh * ENCc;
    __bf16* linWb  = bp; bp += (size_t)NPAD * Hh;
    __bf16* embg   = bp; bp += (size_t)NSTEP * Bb * Ee;
    __bf16* hall   = bp; bp += (size_t)NSTEP * Bb * Hh;
    __bf16* h0b    = bp; bp += (size_t)Bb * Hh;
    __bf16* emean  = bp; bp += (size_t)Bb * ENCc;
    __bf16* Wcatb  = bp; bp += (size_t)2048 * XDIM;
    __bf16* xb0    = bp; bp += (size_t)Bb * XDIM;
    __bf16* xb1    = bp; bp += (size_t)Bb * XDIM;
    int* ip = (int*)bp;
    int* sort_ind     = ip; ip += Bb;
    int* lens_s       = ip; ip += Bb;
    int* caps_s       = ip; ip += Bb * Tt;
    int* row_emb      = ip; ip += NSTEP * Bb;
    int* logit_rowoff = ip; ip += NSTEP * Bb;
    int* logit_mask   = ip; ip += NSTEP * Bb;

    // 1. sort + maps + int outputs
    k_sort<<<1, Bb, 0, stream>>>(captions, cap_lens, sort_ind, lens_s, caps_s,
                                 row_emb, logit_rowoff, logit_mask, out);
    // 2. preds[:,0,:]
    k_preds0<<<(Bb * Vv + 255) / 256, 256, 0, stream>>>(out);
    // 3. conversions
    k_cvt_enc<<<dim3(2, Bb * Pp), 256, 0, stream>>>(encoder_out, sort_ind, enc_s);
    k_cvt<<<(Aa * ENCc / 4 + 255) / 256, 256, 0, stream>>>(att_enc_W, attW, Aa * ENCc / 4);
    k_cvt<<<(Aa * Ee / 4 + 255) / 256, 256, 0, stream>>>(att_dec_W, attdW, Aa * Ee / 4);
    k_cvt<<<(ENCc * Hh / 4 + 255) / 256, 256, 0, stream>>>(f_beta_W, fbW, ENCc * Hh / 4);
    k_cvt<<<(Hh * ENCc / 4 + 255) / 256, 256, 0, stream>>>(h_init_W, hiW, Hh * ENCc / 4);
    k_cvt<<<(Hh * ENCc / 4 + 255) / 256, 256, 0, stream>>>(c_init_W, ciW, Hh * ENCc / 4);
    k_cvt_lin<<<(NPAD * 128 + 255) / 256, 256, 0, stream>>>(lin_W, linWb);
    k_cvt_emb<<<(NSTEP * Bb * 128) / 256, 256, 0, stream>>>(emb_W, row_emb, embg);
    // 4. enc mean (bf16)
    k_enc_mean<<<dim3(ENCc / 256, Bb), 256, 0, stream>>>(enc_s, emean);
    // 5. h0 (bf16 out) / c0 (f32 out)
    mfma_gemm<1><<<dim3(4, 1), 256, 0, stream>>>(emean, hiW, h_init_b, h0b,
        Bb, Hh, ENCc, Hh, nullptr, nullptr, nullptr);
    mfma_gemm<0><<<dim3(4, 1), 256, 0, stream>>>(emean, ciW, c_init_b, cbuf,
        Bb, Hh, ENCc, Hh, nullptr, nullptr, nullptr);
    // 6. att_enc (M=25088,N=512,K=2048) -> bf16
    mfma_gemm<1><<<dim3(4, Bb * Pp / 128), 256, 0, stream>>>(enc_s, attW, att_enc_b, attenc,
        Bb * Pp, Aa, ENCc, Aa, nullptr, nullptr, nullptr);
    // 7. att_d (M=3072,N=512,K=512) -> f32
    mfma_gemm<0><<<dim3(4, NSTEP * Bb / 128), 256, 0, stream>>>(embg, attdW, att_dec_b, att_d,
        NSTEP * Bb, Aa, Ee, Aa, nullptr, nullptr, nullptr);
    // 8. scores / softmax / ctx
    k_scores<<<dim3((Pp + PCHUNK - 1) / PCHUNK, Bb), 256, 0, stream>>>(attenc, att_d, att_fin_W, att_fin_b, wts);
    k_softmax<<<NSTEP * Bb, 64, 0, stream>>>(wts);
    k_ctx<<<dim3(ENCc / 256, Bb), 256, 0, stream>>>(enc_s, wts, ctx_raw);
    // 9. W_cat bf16
    k_wcat<<<dim3(XDIM / 1024, 2048), 256, 0, stream>>>(W_ih, W_hh, Wcatb);
    // 10. x0 init
    k_init_x<<<(Bb * Hh) / 256, 256, 0, stream>>>(h0b, embg, xb0);

    // 11. sequential LSTM loop
    for (int t = 0; t < NSTEP; t++) {
        __bf16* xc = (t & 1) ? xb1 : xb0;
        __bf16* xn = (t & 1) ? xb0 : xb1;
        const __bf16* hprev = (t == 0) ? h0b : (hall + (size_t)(t - 1) * Bb * Hh);
        // gate = sigmoid(h @ f_beta_W^T + b) * ctx_raw[t] -> x[:, :2048] (bf16)
        mfma_gemm<3><<<dim3(16, 1), 256, 0, stream>>>(hprev, fbW, f_beta_b, xc,
            Bb, ENCc, Hh, XDIM, nullptr, nullptr, ctx_raw + (size_t)t * Bb * ENCc);
        // gates = x @ W_cat^T  (bias folded into k_lstm)
        mfma_gemm<0><<<dim3(16, 1), 256, 0, stream>>>(xc, Wcatb, nullptr, gates,
            Bb, 2048, XDIM, 2048, nullptr, nullptr, nullptr);
        // pointwise LSTM
        k_lstm<<<(Bb * Hh) / 256, 256, 0, stream>>>(gates, cbuf, hprev,
            hall + (size_t)t * Bb * Hh, xn,
            (t + 1 < NSTEP) ? (embg + (size_t)(t + 1) * Bb * Ee) : nullptr,
            b_ih, b_hh, lens_s, t);
    }

    // 12. logits (M=3072, N=10000 padded to 10112, K=512), scatter+mask into preds
    mfma_gemm<2><<<dim3(NPAD / 128, NSTEP * Bb / 128), 256, 0, stream>>>(hall, linWb, lin_b, out,
        NSTEP * Bb, Vv, Hh, 0, logit_rowoff, logit_mask, nullptr);
}

// Round 4
// 2278.199 us; speedup vs baseline: 4.5972x; 1.5496x over previous
//
#include <hip/hip_runtime.h>
#include <hip/hip_cooperative_groups.h>
#include <math.h>

namespace cg = cooperative_groups;

#define Bb 128
#define Tt 25
#define Vv 10000
#define Ee 512
#define Aa 512
#define Hh 512
#define ENCc 2048
#define Pp 196
#define NSTEP 24
#define NPAD 10112  // 79*128
#define NWG 64      // cooperative loop workgroups

#define OUT_CAPS  ((size_t)Bb*Tt*Vv)            // 32,000,000
#define OUT_LENS  (OUT_CAPS + (size_t)Bb*Tt)    // 32,003,200
#define OUT_SORT  (OUT_LENS + Bb)               // 32,003,328

typedef __bf16 bf16x8 __attribute__((ext_vector_type(8)));
typedef __bf16 bf16x4 __attribute__((ext_vector_type(4)));
typedef float  f32x4  __attribute__((ext_vector_type(4)));

__device__ __forceinline__ float sigm(float x) { return 1.0f / (1.0f + expf(-x)); }

// ---------------- sort + index maps + int outputs ----------------
__global__ void k_sort(const int* __restrict__ captions, const int* __restrict__ cap_lens,
                       int* sort_ind, int* lens_s, int* caps_s,
                       int* row_emb, int* logit_rowoff, int* logit_mask,
                       float* out)
{
    int b = threadIdx.x; // 0..127
    __shared__ int lens_sh[Bb];
    int len = cap_lens[b];
    lens_sh[b] = len;
    __syncthreads();
    int r = 0;
    for (int k = 0; k < Bb; k++) {
        int lk = lens_sh[k];
        if (lk > len || (lk == len && k < b)) r++;
    }
    sort_ind[r] = b;
    lens_s[r] = len;
    for (int t = 0; t < Tt; t++) {
        int cv = captions[b * Tt + t];
        caps_s[r * Tt + t] = cv;
        out[OUT_CAPS + (size_t)r * Tt + t] = (float)cv;
    }
    out[OUT_LENS + r] = (float)len;
    out[OUT_SORT + r] = (float)b;
    __syncthreads();
    for (int m = b; m < NSTEP * Bb; m += Bb) {
        int t = m / Bb, bb = m % Bb;
        row_emb[m] = caps_s[bb * Tt + t];
        logit_rowoff[m] = (bb * Tt + (t + 1)) * Vv;
        logit_mask[m] = (lens_s[bb] > t + 1) ? 1 : 0;
    }
}

__global__ void k_preds0(float* out)
{
    size_t i = (size_t)blockIdx.x * 256 + threadIdx.x;
    if (i >= (size_t)Bb * Vv) return;
    size_t b = i / Vv, v = i % Vv;
    out[b * Tt * Vv + v] = (v == 0) ? 1.0f : 0.0f;
}

// bias2 = b_ih + b_hh ; bias_att = att_enc_b + att_dec_b
__global__ void k_bias(const float* b_ih, const float* b_hh,
                       const float* aeb, const float* adb,
                       float* bias2, float* bias_att)
{
    int i = blockIdx.x * 256 + threadIdx.x;
    if (i < 2048) bias2[i] = b_ih[i] + b_hh[i];
    if (i < 512)  bias_att[i] = aeb[i] + adb[i];
}

// ---------------- conversions ----------------
__global__ void k_cvt_enc(const float* __restrict__ src, const int* __restrict__ sind,
                          __bf16* __restrict__ dst)
{
    int row = blockIdx.y;                       // sorted row
    int e4 = blockIdx.x * 256 + threadIdx.x;
    int b = row / Pp, p = row % Pp;
    const float4 v = *(const float4*)(src + ((size_t)(sind[b] * Pp + p)) * ENCc + e4 * 4);
    bf16x4 o = { (__bf16)v.x, (__bf16)v.y, (__bf16)v.z, (__bf16)v.w };
    *(bf16x4*)(dst + (size_t)row * ENCc + e4 * 4) = o;
}

__global__ void k_cvt(const float* __restrict__ src, __bf16* __restrict__ dst, int n4)
{
    int i = blockIdx.x * 256 + threadIdx.x;
    if (i >= n4) return;
    const float4 v = *(const float4*)(src + (size_t)i * 4);
    bf16x4 o = { (__bf16)v.x, (__bf16)v.y, (__bf16)v.z, (__bf16)v.w };
    *(bf16x4*)(dst + (size_t)i * 4) = o;
}

__global__ void k_cvt_lin(const float* __restrict__ src, __bf16* __restrict__ dst)
{
    int i = blockIdx.x * 256 + threadIdx.x;     // over NPAD*128
    if (i >= NPAD * 128) return;
    int row = i >> 7, e = (i & 127) * 4;
    bf16x4 o;
    if (row < Vv) {
        const float4 v = *(const float4*)(src + (size_t)row * Hh + e);
        o = bf16x4{ (__bf16)v.x, (__bf16)v.y, (__bf16)v.z, (__bf16)v.w };
    } else {
        o = bf16x4{ (__bf16)0.f, (__bf16)0.f, (__bf16)0.f, (__bf16)0.f };
    }
    *(bf16x4*)(dst + (size_t)row * Hh + e) = o;
}

__global__ void k_cvt_emb(const float* __restrict__ emb_W, const int* __restrict__ row_emb,
                          __bf16* __restrict__ dst)
{
    int i = blockIdx.x * 256 + threadIdx.x;     // over 3072*128
    int row = i >> 7, e = (i & 127) * 4;
    const float4 v = *(const float4*)(emb_W + (size_t)row_emb[row] * Ee + e);
    bf16x4 o = { (__bf16)v.x, (__bf16)v.y, (__bf16)v.z, (__bf16)v.w };
    *(bf16x4*)(dst + (size_t)row * Ee + e) = o;
}

// Wihd (2048x512 bf16) = W_ih[:, 2048:2560]
__global__ void k_cvt_wihd(const float* __restrict__ W_ih, __bf16* __restrict__ dst)
{
    int i = blockIdx.x * 256 + threadIdx.x;     // over 2048*128
    int row = i >> 7, e = (i & 127) * 4;
    const float4 v = *(const float4*)(W_ih + (size_t)row * 2560 + 2048 + e);
    bf16x4 o = { (__bf16)v.x, (__bf16)v.y, (__bf16)v.z, (__bf16)v.w };
    *(bf16x4*)(dst + (size_t)row * 512 + e) = o;
}

// W2 (2048x2560 bf16) = [W_ih[:, :2048] | W_hh]
__global__ void k_wcat2(const float* __restrict__ W_ih, const float* __restrict__ W_hh,
                        __bf16* __restrict__ W2)
{
    int n = blockIdx.y;
    int k4 = blockIdx.x * 256 + threadIdx.x;    // 0..639
    if (k4 >= 640) return;
    int k = k4 * 4;
    float4 v;
    if (k < 2048) v = *(const float4*)(W_ih + (size_t)n * 2560 + k);
    else          v = *(const float4*)(W_hh + (size_t)n * 512 + (k - 2048));
    bf16x4 o = { (__bf16)v.x, (__bf16)v.y, (__bf16)v.z, (__bf16)v.w };
    *(bf16x4*)(W2 + (size_t)n * 2560 + k) = o;
}

// ---------------- enc mean (bf16 in, bf16 out) ----------------
__global__ void k_enc_mean(const __bf16* __restrict__ enc, __bf16* __restrict__ emean)
{
    int b = blockIdx.y;
    int e = blockIdx.x * 256 + threadIdx.x;
    const __bf16* base = enc + (size_t)b * Pp * ENCc + e;
    float s = 0.0f;
    for (int p = 0; p < Pp; p++) s += (float)base[(size_t)p * ENCc];
    emean[(size_t)b * ENCc + e] = (__bf16)(s / 196.0f);
}

// ---------------- MFMA GEMM: C = A @ B^T (+bias), 128x128 tile, BK=32 ----------------
// MODE 0: f32 out row-major (stride Nout); MODE 1: bf16 out (stride Nout, col<Ncol)
// MODE 2: f32 out, row scatter (c_rowoff) + mask, col<Ncol
// batched via blockIdx.z with element strides bsA/bsB/bsC
template<int MODE>
__launch_bounds__(256)
__global__ void mfma_gemm(const __bf16* __restrict__ A, const __bf16* __restrict__ B,
                          const float* __restrict__ bias, void* __restrict__ Cout,
                          int K, int Nout, int Ncol,
                          const int* __restrict__ c_rowoff,
                          const int* __restrict__ mmask,
                          size_t bsA, size_t bsB, size_t bsC)
{
    __shared__ __bf16 sA[128 * 32];
    __shared__ __bf16 sB[128 * 32];
    const int tid = threadIdx.x;
    const int lane = tid & 63;
    const int wave = tid >> 6;
    const int z = blockIdx.z;
    const int m0 = blockIdx.y * 128, n0 = blockIdx.x * 128;
    const int wr = (wave & 1) * 64, wc = (wave >> 1) * 64;
    f32x4 acc[4][4] = {};
    const __bf16* Aptr = A + bsA * z + (size_t)m0 * K;
    const __bf16* Bptr = B + bsB * z + (size_t)n0 * K;
    const int c0 = tid, c1 = tid + 256;
    const int ar0 = c0 >> 2, ak0 = (c0 & 3) * 8;
    const int ar1 = c1 >> 2, ak1 = (c1 & 3) * 8;
    const int kq = (lane >> 4) * 8, mr = lane & 15;

    for (int k0 = 0; k0 < K; k0 += 32) {
        __builtin_amdgcn_global_load_lds(
            (const __attribute__((address_space(1))) void*)(Aptr + (size_t)ar0 * K + k0 + ak0),
            (__attribute__((address_space(3))) void*)(sA + c0 * 8), 16, 0, 0);
        __builtin_amdgcn_global_load_lds(
            (const __attribute__((address_space(1))) void*)(Aptr + (size_t)ar1 * K + k0 + ak1),
            (__attribute__((address_space(3))) void*)(sA + c1 * 8), 16, 0, 0);
        __builtin_amdgcn_global_load_lds(
            (const __attribute__((address_space(1))) void*)(Bptr + (size_t)ar0 * K + k0 + ak0),
            (__attribute__((address_space(3))) void*)(sB + c0 * 8), 16, 0, 0);
        __builtin_amdgcn_global_load_lds(
            (const __attribute__((address_space(1))) void*)(Bptr + (size_t)ar1 * K + k0 + ak1),
            (__attribute__((address_space(3))) void*)(sB + c1 * 8), 16, 0, 0);
        __syncthreads();
        bf16x8 af[4], bfr[4];
        #pragma unroll
        for (int i = 0; i < 4; i++)
            af[i] = *(const bf16x8*)(sA + (wr + i * 16 + mr) * 32 + kq);
        #pragma unroll
        for (int j = 0; j < 4; j++)
            bfr[j] = *(const bf16x8*)(sB + (wc + j * 16 + mr) * 32 + kq);
        #pragma unroll
        for (int i = 0; i < 4; i++)
            #pragma unroll
            for (int j = 0; j < 4; j++)
                acc[i][j] = __builtin_amdgcn_mfma_f32_16x16x32_bf16(af[i], bfr[j], acc[i][j], 0, 0, 0);
        __syncthreads();
    }

    const int rq = (lane >> 4) * 4, cq = lane & 15;
    #pragma unroll
    for (int i = 0; i < 4; i++) {
        #pragma unroll
        for (int j = 0; j < 4; j++) {
            #pragma unroll
            for (int r = 0; r < 4; r++) {
                int row = m0 + wr + i * 16 + rq + r;
                int col = n0 + wc + j * 16 + cq;
                if ((MODE == 1 || MODE == 2) && col >= Ncol) continue;
                float v = acc[i][j][r] + (bias ? bias[col] : 0.0f);
                size_t ro = (c_rowoff ? (size_t)c_rowoff[row] : (size_t)row * Nout) + bsC * z;
                if (MODE == 2) {
                    if (!mmask[row]) v = 0.0f;
                    ((float*)Cout)[ro + col] = v;
                } else if (MODE == 1) {
                    ((__bf16*)Cout)[ro + col] = (__bf16)v;
                } else {
                    ((float*)Cout)[ro + col] = v;
                }
            }
        }
    }
}

// ---------------- scores v3: reduction-free, lane<->p ----------------
// ET[b][a][196] bf16 (attenc^T, no bias), D = att_d[t*128+b][512] f32 (both biases folded)
__global__ void k_scores(const __bf16* __restrict__ ET, const float* __restrict__ att_d,
                         const float* __restrict__ fin_W, const float* __restrict__ fin_b,
                         float* __restrict__ wts)
{
    __shared__ float Dls[512 * 12];
    const int b = blockIdx.y;
    const int tb = blockIdx.x * 12;
    const int tid = threadIdx.x;
    #pragma unroll
    for (int tt = 0; tt < 12; tt++)
        for (int a = tid; a < 512; a += 256)
            Dls[a * 12 + tt] = att_d[((size_t)(tb + tt) * Bb + b) * Aa + a];
    __syncthreads();
    const int p = tid;
    if (p >= Pp) return;
    float acc[12];
    #pragma unroll
    for (int i = 0; i < 12; i++) acc[i] = 0.0f;
    const __bf16* ep = ET + (size_t)b * Aa * Pp + p;
    for (int a = 0; a < 512; a++) {
        float e = (float)ep[(size_t)a * Pp];
        float fw = fin_W[a];
        const float4* dp = (const float4*)(Dls + a * 12);
        float4 d0 = dp[0], d1 = dp[1], d2 = dp[2];
        acc[0] += fmaxf(e + d0.x, 0.0f) * fw;
        acc[1] += fmaxf(e + d0.y, 0.0f) * fw;
        acc[2] += fmaxf(e + d0.z, 0.0f) * fw;
        acc[3] += fmaxf(e + d0.w, 0.0f) * fw;
        acc[4] += fmaxf(e + d1.x, 0.0f) * fw;
        acc[5] += fmaxf(e + d1.y, 0.0f) * fw;
        acc[6] += fmaxf(e + d1.z, 0.0f) * fw;
        acc[7] += fmaxf(e + d1.w, 0.0f) * fw;
        acc[8] += fmaxf(e + d2.x, 0.0f) * fw;
        acc[9] += fmaxf(e + d2.y, 0.0f) * fw;
        acc[10] += fmaxf(e + d2.z, 0.0f) * fw;
        acc[11] += fmaxf(e + d2.w, 0.0f) * fw;
    }
    float fb = fin_b[0];
    #pragma unroll
    for (int tt = 0; tt < 12; tt++)
        wts[((size_t)(tb + tt) * Bb + b) * Pp + p] = acc[tt] + fb;
}

__global__ void k_softmax(float* scores)
{
    int tb = blockIdx.x;
    float* row = scores + (size_t)tb * Pp;
    int lane = threadIdx.x; // 64
    float v[4];
    float mx = -1e30f;
    #pragma unroll
    for (int i = 0; i < 4; i++) {
        int p = lane + i * 64;
        v[i] = (p < Pp) ? row[p] : -1e30f;
        mx = fmaxf(mx, v[i]);
    }
    #pragma unroll
    for (int off = 32; off > 0; off >>= 1) mx = fmaxf(mx, __shfl_down(mx, off));
    mx = __shfl(mx, 0);
    float s = 0.0f;
    #pragma unroll
    for (int i = 0; i < 4; i++) {
        int p = lane + i * 64;
        v[i] = (p < Pp) ? expf(v[i] - mx) : 0.0f;
        s += v[i];
    }
    #pragma unroll
    for (int off = 32; off > 0; off >>= 1) s += __shfl_down(s, off);
    s = __shfl(s, 0);
    float inv = 1.0f / s;
    #pragma unroll
    for (int i = 0; i < 4; i++) {
        int p = lane + i * 64;
        if (p < Pp) row[p] = v[i] * inv;
    }
}

// ---------------- ctx_raw[t,b,:] = sum_p wts[t,b,p] * enc_s[b,p,:] ----------------
__global__ void k_ctx(const __bf16* __restrict__ enc, const float* __restrict__ wts,
                      float* __restrict__ ctx_raw)
{
    int b = blockIdx.y;
    int e = blockIdx.x * 256 + threadIdx.x;
    __shared__ float w_s[NSTEP][Pp];
    int tid = threadIdx.x;
    for (int idx = tid; idx < NSTEP * Pp; idx += 256) {
        int t = idx / Pp, p = idx % Pp;
        w_s[t][p] = wts[((size_t)t * Bb + b) * Pp + p];
    }
    __syncthreads();
    const __bf16* base = enc + (size_t)b * Pp * ENCc + e;
    float acc[NSTEP];
    #pragma unroll
    for (int t = 0; t < NSTEP; t++) acc[t] = 0.0f;
    for (int p = 0; p < Pp; p++) {
        float v = (float)base[(size_t)p * ENCc];
        #pragma unroll
        for (int t = 0; t < NSTEP; t++) acc[t] += w_s[t][p] * v;
    }
    for (int t = 0; t < NSTEP; t++)
        ctx_raw[((size_t)t * Bb + b) * ENCc + e] = acc[t];
}

// ---------------- fused recurrence (cooperative, NWG=64 x 256) ----------------
// stage A: G = h @ fbW^T (128x2048,K=512); xctx = bf16(sigm(G+fbb)*ctx_raw[t])
// stage B: gates strips (4 gates x 8 cols per WG), K=2560 over [xctx|hcur]; LSTM epilogue
__device__ __forceinline__ bf16x8 lds_frag(const __bf16* s, int row, int g)
{
    int slot = row * 16 + (g ^ (row & 7));
    return *(const bf16x8*)(s + slot * 8);
}

__launch_bounds__(256)
__global__ void k_loop(__bf16* __restrict__ xctx, __bf16* __restrict__ hbuf0,
                       __bf16* __restrict__ hbuf1, float* __restrict__ cbuf,
                       const float* __restrict__ ctx_raw,
                       const __bf16* __restrict__ fbW, const float* __restrict__ fbb,
                       const __bf16* __restrict__ W2, const float* __restrict__ gdec,
                       __bf16* __restrict__ hall, const int* __restrict__ lens)
{
    cg::grid_group grid = cg::this_grid();
    __shared__ __bf16 sA[128 * 128];   // 32 KB
    __shared__ __bf16 sB[32 * 128];    // 8 KB
    const int tid = threadIdx.x, lane = tid & 63, wave = tid >> 6;
    const int wg = blockIdx.x;
    const int cq = lane & 15, rq4 = (lane >> 4) * 4;
    const int mbase = wave * 32;
    const int kq = lane >> 4;          // k-granule sub-index

    for (int t = 0; t < NSTEP; t++) {
        const __bf16* hcur = (t & 1) ? hbuf1 : hbuf0;
        __bf16* hnext = (t & 1) ? hbuf0 : hbuf1;
        // ---------- stage A ----------
        {
            const int cb = wg * 32;
            f32x4 acc[2][2] = {};
            for (int k0 = 0; k0 < 512; k0 += 128) {
                #pragma unroll
                for (int i = 0; i < 8; i++) {
                    int flat = tid + 256 * i;
                    int row = flat >> 4, gs = flat & 15;
                    int gsrc = gs ^ (row & 7);
                    __builtin_amdgcn_global_load_lds(
                        (const __attribute__((address_space(1))) void*)(hcur + (size_t)row * 512 + k0 + gsrc * 8),
                        (__attribute__((address_space(3))) void*)(sA + flat * 8), 16, 0, 0);
                }
                #pragma unroll
                for (int i = 0; i < 2; i++) {
                    int flat = tid + 256 * i;
                    int row = flat >> 4, gs = flat & 15;
                    int gsrc = gs ^ (row & 7);
                    __builtin_amdgcn_global_load_lds(
                        (const __attribute__((address_space(1))) void*)(fbW + (size_t)(cb + row) * 512 + k0 + gsrc * 8),
                        (__attribute__((address_space(3))) void*)(sB + flat * 8), 16, 0, 0);
                }
                __syncthreads();
                #pragma unroll
                for (int ks = 0; ks < 4; ks++) {
                    int g = ks * 4 + kq;
                    bf16x8 af[2], bfv[2];
                    #pragma unroll
                    for (int mi = 0; mi < 2; mi++) af[mi] = lds_frag(sA, mbase + mi * 16 + cq, g);
                    #pragma unroll
                    for (int ni = 0; ni < 2; ni++) bfv[ni] = lds_frag(sB, ni * 16 + cq, g);
                    #pragma unroll
                    for (int mi = 0; mi < 2; mi++)
                        #pragma unroll
                        for (int ni = 0; ni < 2; ni++)
                            acc[mi][ni] = __builtin_amdgcn_mfma_f32_16x16x32_bf16(af[mi], bfv[ni], acc[mi][ni], 0, 0, 0);
                }
                __syncthreads();
            }
            const float* cr = ctx_raw + (size_t)t * Bb * ENCc;
            #pragma unroll
            for (int mi = 0; mi < 2; mi++)
                #pragma unroll
                for (int ni = 0; ni < 2; ni++)
                    #pragma unroll
                    for (int r = 0; r < 4; r++) {
                        int row = mbase + mi * 16 + rq4 + r;
                        int col = cb + ni * 16 + cq;
                        float v = acc[mi][ni][r] + fbb[col];
                        float x = sigm(v) * cr[(size_t)row * ENCc + col];
                        xctx[(size_t)row * ENCc + col] = (__bf16)x;
                    }
        }
        grid.sync();
        // ---------- stage B ----------
        {
            const int jb = wg * 8;
            f32x4 acc[2][2] = {};
            for (int k0 = 0; k0 < 2560; k0 += 128) {
                const bool inH = (k0 >= 2048);
                #pragma unroll
                for (int i = 0; i < 8; i++) {
                    int flat = tid + 256 * i;
                    int row = flat >> 4, gs = flat & 15;
                    int gsrc = gs ^ (row & 7);
                    const __bf16* src = inH ? (hcur + (size_t)row * 512 + (k0 - 2048) + gsrc * 8)
                                            : (xctx + (size_t)row * ENCc + k0 + gsrc * 8);
                    __builtin_amdgcn_global_load_lds(
                        (const __attribute__((address_space(1))) void*)src,
                        (__attribute__((address_space(3))) void*)(sA + flat * 8), 16, 0, 0);
                }
                #pragma unroll
                for (int i = 0; i < 2; i++) {
                    int flat = tid + 256 * i;
                    int row = flat >> 4, gs = flat & 15;
                    int gsrc = gs ^ (row & 7);
                    int wrow = (row >> 3) * 512 + jb + (row & 7);
                    __builtin_amdgcn_global_load_lds(
                        (const __attribute__((address_space(1))) void*)(W2 + (size_t)wrow * 2560 + k0 + gsrc * 8),
                        (__attribute__((address_space(3))) void*)(sB + flat * 8), 16, 0, 0);
                }
                __syncthreads();
                #pragma unroll
                for (int ks = 0; ks < 4; ks++) {
                    int g = ks * 4 + kq;
                    bf16x8 af[2], bfv[2];
                    #pragma unroll
                    for (int mi = 0; mi < 2; mi++) af[mi] = lds_frag(sA, mbase + mi * 16 + cq, g);
                    #pragma unroll
                    for (int ni = 0; ni < 2; ni++) bfv[ni] = lds_frag(sB, ni * 16 + cq, g);
                    #pragma unroll
                    for (int mi = 0; mi < 2; mi++)
                        #pragma unroll
                        for (int ni = 0; ni < 2; ni++)
                            acc[mi][ni] = __builtin_amdgcn_mfma_f32_16x16x32_bf16(af[mi], bfv[ni], acc[mi][ni], 0, 0, 0);
                }
                __syncthreads();
            }
            // LSTM epilogue: lane cq<8 holds (i,g); partner cq+8 holds (f,o)
            const int j = jb + (cq & 7);
            const int g0 = cq >> 3;
            #pragma unroll
            for (int mi = 0; mi < 2; mi++)
                #pragma unroll
                for (int r = 0; r < 4; r++) {
                    int row = mbase + mi * 16 + rq4 + r;
                    size_t gb = (size_t)(t * Bb + row) * 2048;
                    float a0 = acc[mi][0][r] + gdec[gb + (size_t)g0 * 512 + j];
                    float a1 = acc[mi][1][r] + gdec[gb + (size_t)(2 + g0) * 512 + j];
                    float p0 = __shfl_xor(a0, 8);
                    float p1 = __shfl_xor(a1, 8);
                    float iv, fv, gv, ov;
                    if (cq < 8) { iv = a0; gv = a1; fv = p0; ov = p1; }
                    else        { iv = p0; gv = p1; fv = a0; ov = a1; }
                    float co = cbuf[(size_t)row * 512 + j];
                    float cn = sigm(fv) * co + sigm(iv) * tanhf(gv);
                    float hn = sigm(ov) * tanhf(cn);
                    bool act = lens[row] > (t + 1);
                    __bf16 hold = hcur[(size_t)row * 512 + j];
                    __bf16 hv = act ? (__bf16)hn : hold;
                    if (cq < 8) {
                        if (act) cbuf[(size_t)row * 512 + j] = cn;
                        hnext[(size_t)row * 512 + j] = hv;
                        hall[((size_t)t * Bb + row) * 512 + j] = hv;
                    }
                }
        }
        grid.sync();
    }
}

extern "C" void kernel_launch(void* const* d_in, const int* in_sizes, int n_in,
                              void* d_out, int out_size, void* d_ws, size_t ws_size,
                              hipStream_t stream)
{
    const int*   captions    = (const int*)d_in[0];
    const float* encoder_out = (const float*)d_in[1];
    const int*   cap_lens    = (const int*)d_in[2];
    const float* emb_W       = (const float*)d_in[3];
    const float* att_enc_W   = (const float*)d_in[4];
    const float* att_enc_b   = (const float*)d_in[5];
    const float* att_dec_W   = (const float*)d_in[6];
    const float* att_dec_b   = (const float*)d_in[7];
    const float* att_fin_W   = (const float*)d_in[8];
    const float* att_fin_b   = (const float*)d_in[9];
    const float* f_beta_W    = (const float*)d_in[10];
    const float* f_beta_b    = (const float*)d_in[11];
    const float* W_ih        = (const float*)d_in[12];
    const float* b_ih        = (const float*)d_in[13];
    const float* W_hh        = (const float*)d_in[14];
    const float* b_hh        = (const float*)d_in[15];
    const float* lin_W       = (const float*)d_in[16];
    const float* lin_b       = (const float*)d_in[17];
    const float* h_init_W    = (const float*)d_in[18];
    const float* h_init_b    = (const float*)d_in[19];
    const float* c_init_W    = (const float*)d_in[20];
    const float* c_init_b    = (const float*)d_in[21];
    float* out = (float*)d_out;

    // ---- workspace carve ----
    float* f = (float*)d_ws;
    float* ctx_raw  = f; f += (size_t)NSTEP * Bb * ENCc;   // 6.29M
    float* att_d    = f; f += (size_t)NSTEP * Bb * Aa;     // 1.57M
    float* wts      = f; f += (size_t)NSTEP * Bb * Pp;     // 602k
    float* cbuf     = f; f += (size_t)Bb * Hh;
    float* gdec     = f; f += (size_t)NSTEP * Bb * 2048;   // 6.29M
    float* bias2    = f; f += 2048;
    float* bias_att = f; f += 512;
    __bf16* bp = (__bf16*)f;
    __bf16* enc_s = bp; bp += (size_t)Bb * Pp * ENCc + 131072;  // + guard pad
    __bf16* ET    = bp; bp += (size_t)Bb * Aa * Pp;             // 12.85M
    __bf16* attW  = bp; bp += (size_t)Aa * ENCc;
    __bf16* attdW = bp; bp += (size_t)Aa * Ee;
    __bf16* fbW   = bp; bp += (size_t)ENCc * Hh;
    __bf16* hiW   = bp; bp += (size_t)Hh * ENCc;
    __bf16* ciW   = bp; bp += (size_t)Hh * ENCc;
    __bf16* linWb = bp; bp += (size_t)NPAD * Hh;
    __bf16* embg  = bp; bp += (size_t)NSTEP * Bb * Ee;
    __bf16* hall  = bp; bp += (size_t)NSTEP * Bb * Hh;
    __bf16* hbuf0 = bp; bp += (size_t)Bb * Hh;
    __bf16* hbuf1 = bp; bp += (size_t)Bb * Hh;
    __bf16* emean = bp; bp += (size_t)Bb * ENCc;
    __bf16* W2    = bp; bp += (size_t)2048 * 2560;
    __bf16* Wihd  = bp; bp += (size_t)2048 * 512;
    __bf16* xctx  = bp; bp += (size_t)Bb * ENCc;
    int* ip = (int*)bp;
    int* sort_ind     = ip; ip += Bb;
    int* lens_s       = ip; ip += Bb;
    int* caps_s       = ip; ip += Bb * Tt;
    int* row_emb      = ip; ip += NSTEP * Bb;
    int* logit_rowoff = ip; ip += NSTEP * Bb;
    int* logit_mask   = ip; ip += NSTEP * Bb;

    // 1. sort + maps + int outputs ; preds[:,0] ; combined biases
    k_sort<<<1, Bb, 0, stream>>>(captions, cap_lens, sort_ind, lens_s, caps_s,
                                 row_emb, logit_rowoff, logit_mask, out);
    k_preds0<<<(Bb * Vv + 255) / 256, 256, 0, stream>>>(out);
    k_bias<<<8, 256, 0, stream>>>(b_ih, b_hh, att_enc_b, att_dec_b, bias2, bias_att);
    // 2. conversions
    k_cvt_enc<<<dim3(2, Bb * Pp), 256, 0, stream>>>(encoder_out, sort_ind, enc_s);
    k_cvt<<<(Aa * ENCc / 4 + 255) / 256, 256, 0, stream>>>(att_enc_W, attW, Aa * ENCc / 4);
    k_cvt<<<(Aa * Ee / 4 + 255) / 256, 256, 0, stream>>>(att_dec_W, attdW, Aa * Ee / 4);
    k_cvt<<<(ENCc * Hh / 4 + 255) / 256, 256, 0, stream>>>(f_beta_W, fbW, ENCc * Hh / 4);
    k_cvt<<<(Hh * ENCc / 4 + 255) / 256, 256, 0, stream>>>(h_init_W, hiW, Hh * ENCc / 4);
    k_cvt<<<(Hh * ENCc / 4 + 255) / 256, 256, 0, stream>>>(c_init_W, ciW, Hh * ENCc / 4);
    k_cvt_lin<<<(NPAD * 128 + 255) / 256, 256, 0, stream>>>(lin_W, linWb);
    k_cvt_emb<<<(NSTEP * Bb * 128) / 256, 256, 0, stream>>>(emb_W, row_emb, embg);
    k_cvt_wihd<<<(2048 * 128) / 256, 256, 0, stream>>>(W_ih, Wihd);
    k_wcat2<<<dim3(3, 2048), 256, 0, stream>>>(W_ih, W_hh, W2);
    // 3. enc mean ; h0 -> hbuf0 (bf16) ; c0 -> cbuf (f32)
    k_enc_mean<<<dim3(ENCc / 256, Bb), 256, 0, stream>>>(enc_s, emean);
    mfma_gemm<1><<<dim3(4, 1), 256, 0, stream>>>(emean, hiW, h_init_b, hbuf0,
        ENCc, Hh, 512, nullptr, nullptr, 0, 0, 0);
    mfma_gemm<0><<<dim3(4, 1), 256, 0, stream>>>(emean, ciW, c_init_b, cbuf,
        ENCc, Hh, 512, nullptr, nullptr, 0, 0, 0);
    // 4. ET[b] = attW @ enc_s[b]^T  (batched, M=512, N=196 padded 256, K=2048) -> bf16
    mfma_gemm<1><<<dim3(2, 4, Bb), 256, 0, stream>>>(attW, enc_s, nullptr, ET,
        ENCc, Pp, Pp, nullptr, nullptr, 0, (size_t)Pp * ENCc, (size_t)Aa * Pp);
    // 5. att_d (M=3072, N=512, K=512), combined bias
    mfma_gemm<0><<<dim3(4, NSTEP * Bb / 128), 256, 0, stream>>>(embg, attdW, bias_att, att_d,
        Ee, Aa, 512, nullptr, nullptr, 0, 0, 0);
    // 6. gdec = embg @ Wihd^T + bias2 (M=3072, N=2048, K=512)
    mfma_gemm<0><<<dim3(16, NSTEP * Bb / 128), 256, 0, stream>>>(embg, Wihd, bias2, gdec,
        Ee, 2048, 2048, nullptr, nullptr, 0, 0, 0);
    // 7. scores / softmax / ctx
    k_scores<<<dim3(2, Bb), 256, 0, stream>>>(ET, att_d, att_fin_W, att_fin_b, wts);
    k_softmax<<<NSTEP * Bb, 64, 0, stream>>>(wts);
    k_ctx<<<dim3(ENCc / 256, Bb), 256, 0, stream>>>(enc_s, wts, ctx_raw);
    // 8. fused recurrence (cooperative)
    {
        void* args[] = { &xctx, &hbuf0, &hbuf1, &cbuf, &ctx_raw, &fbW,
                         (void*)&f_beta_b, &W2, &gdec, &hall, &lens_s };
        hipLaunchCooperativeKernel((void*)k_loop, dim3(NWG), dim3(256), args, 0, stream);
    }
    // 9. logits (M=3072, N=10000 pad 10112, K=512), scatter+mask into preds
    mfma_gemm<2><<<dim3(NPAD / 128, NSTEP * Bb / 128), 256, 0, stream>>>(hall, linWb, lin_b, out,
        Hh, 0, Vv, logit_rowoff, logit_mask, 0, 0, 0);
}